// Round 1
// baseline (162.213 us; speedup 1.0000x reference)
//
#include <hip/hip_runtime.h>
#include <hip/hip_bf16.h>

typedef __attribute__((ext_vector_type(8))) short bf16x8;
typedef __attribute__((ext_vector_type(4))) short short4v;
typedef __attribute__((ext_vector_type(4))) float f32x4;

#define B_SZ 8
#define T_SZ 2048
#define C_SZ 768
#define H_SZ 64

__device__ __forceinline__ short f2bs(float f){
  __hip_bfloat16 h = __float2bfloat16(f);
  short s; __builtin_memcpy(&s, &h, 2); return s;
}

// --- Kernel 0: W -> Wt[192][768] bf16 (transposed, q|k|v concatenated) ---
__global__ void prep_wt(const float* __restrict__ Wq, const float* __restrict__ Wk,
                        const float* __restrict__ Wv, short* __restrict__ Wt){
  int n = blockIdx.x;                       // 0..191 output column
  const float* W = (n < 64) ? Wq : (n < 128 ? Wk : Wv);
  int c = n & 63;
  for (int k = threadIdx.x; k < C_SZ; k += blockDim.x)
    Wt[n*C_SZ + k] = f2bs(W[k*H_SZ + c]);
}

// --- Kernel 1: QKV projection GEMM. x[16384,768] @ Wt^T -> q,k (row-major bf16), vT[b][d][t] ---
__global__ __launch_bounds__(512) void qkv_gemm(const float* __restrict__ x, const short* __restrict__ Wt,
                         short* __restrict__ qb, short* __restrict__ kb, short* __restrict__ vT){
  __shared__ short As[64][40];              // +8 pad: 80B row stride, 16B-aligned, 2-way banks
  int tid  = threadIdx.x;
  int wave = tid >> 6, lane = tid & 63;
  int lhi = lane >> 4, llo = lane & 15;
  int wm = wave >> 1, wn = wave & 1;        // 4 M-groups x 2 N-groups
  long m0 = (long)blockIdx.x * 64;

  f32x4 acc[6];
  #pragma unroll
  for (int j = 0; j < 6; ++j) acc[j] = (f32x4){0.f,0.f,0.f,0.f};

  int r = tid >> 3, koff = (tid & 7) * 4;   // staging assignment
  const short* aAddr = &As[wm*16 + llo][lhi*8];

  for (int k0 = 0; k0 < C_SZ; k0 += 32){
    float4 xa = *reinterpret_cast<const float4*>(&x[(m0 + r)*C_SZ + k0 + koff]);
    short4v a4;
    a4[0]=f2bs(xa.x); a4[1]=f2bs(xa.y); a4[2]=f2bs(xa.z); a4[3]=f2bs(xa.w);
    *reinterpret_cast<short4v*>(&As[r][koff]) = a4;
    __syncthreads();
    bf16x8 af = *reinterpret_cast<const bf16x8*>(aAddr);
    #pragma unroll
    for (int j = 0; j < 6; ++j){
      int n = wn*96 + j*16 + llo;
      bf16x8 bf = *reinterpret_cast<const bf16x8*>(&Wt[n*C_SZ + k0 + lhi*8]);
      acc[j] = __builtin_amdgcn_mfma_f32_16x16x32_bf16(af, bf, acc[j], 0, 0, 0);
    }
    __syncthreads();
  }

  // epilogue: cols 0-63 -> q, 64-127 -> k, 128-191 -> v (transposed store)
  #pragma unroll
  for (int j = 0; j < 6; ++j){
    int n = wn*96 + j*16 + llo;
    int mat = n >> 6, c = n & 63;
    long mbase = m0 + wm*16 + lhi*4;
    if (mat == 2){
      long b = mbase >> 11, t = mbase & 2047;
      short4v p;
      #pragma unroll
      for (int reg = 0; reg < 4; ++reg) p[reg] = f2bs(acc[j][reg]);
      *reinterpret_cast<short4v*>(&vT[(b*H_SZ + c)*T_SZ + t]) = p;
    } else {
      short* dst = (mat == 0) ? qb : kb;
      #pragma unroll
      for (int reg = 0; reg < 4; ++reg)
        dst[(mbase + reg)*H_SZ + c] = f2bs(acc[j][reg]);
    }
  }
}

// --- Kernel 2: per-wave flash attention, QB=16, KVB=64, paired q-tiles for balance ---
__global__ __launch_bounds__(128) void attn_fwd(const short* __restrict__ qb, const short* __restrict__ kb,
                        const short* __restrict__ vT, const float* __restrict__ bias_table,
                        float* __restrict__ out){
  __shared__ float bias_s[2048];
  __shared__ short P_lds[2][16][72];        // per-wave P tile, +8 pad
  int tid = threadIdx.x;
  #pragma unroll
  for (int i = 0; i < 16; ++i) bias_s[tid + i*128] = bias_table[tid + i*128];
  __syncthreads();

  int wv = tid >> 6, lane = tid & 63;
  int lhi = lane >> 4, llo = lane & 15;
  int wid = blockIdx.x * 2 + wv;            // 0..511
  int b = wid >> 6, jj = wid & 63;

  for (int rep = 0; rep < 2; ++rep){
    int qt = (rep == 0) ? jj : (127 - jj);  // paired: work = qt/4+1 sums to const 33
    int q0 = qt * 16;
    const short* qrow = &qb[((long)(b*T_SZ + q0 + llo))*H_SZ + lhi*8];
    bf16x8 qf0 = *reinterpret_cast<const bf16x8*>(qrow);
    bf16x8 qf1 = *reinterpret_cast<const bf16x8*>(qrow + 32);

    float m_r[4], l_r[4];
    f32x4 o[4];
    #pragma unroll
    for (int i2 = 0; i2 < 4; ++i2){ m_r[i2] = -1e30f; l_r[i2] = 0.f; o[i2] = (f32x4){0.f,0.f,0.f,0.f}; }

    int nkt = (qt >> 2) + 1;
    for (int kt = 0; kt < nkt; ++kt){
      int kv0 = kt * 64;
      f32x4 s[4];
      #pragma unroll
      for (int f = 0; f < 4; ++f){
        const short* krow = &kb[((long)(b*T_SZ + kv0 + f*16 + llo))*H_SZ + lhi*8];
        bf16x8 kf0 = *reinterpret_cast<const bf16x8*>(krow);
        bf16x8 kf1 = *reinterpret_cast<const bf16x8*>(krow + 32);
        f32x4 t = (f32x4){0.f,0.f,0.f,0.f};
        t = __builtin_amdgcn_mfma_f32_16x16x32_bf16(qf0, kf0, t, 0, 0, 0);
        t = __builtin_amdgcn_mfma_f32_16x16x32_bf16(qf1, kf1, t, 0, 0, 0);
        s[f] = t;
      }
      // scale + bias + causal mask + online softmax (rows live in regs, cols across llo)
      #pragma unroll
      for (int reg = 0; reg < 4; ++reg){
        int q = q0 + lhi*4 + reg;
        float rm = -1e30f;
        #pragma unroll
        for (int f = 0; f < 4; ++f){
          int kv = kv0 + f*16 + llo;
          int rel = q - kv;                 // causal => rel in [0,2047], no clip needed
          float sv = (rel >= 0) ? (s[f][reg]*0.125f + bias_s[rel]) : -1e30f;
          s[f][reg] = sv;
          rm = fmaxf(rm, sv);
        }
        rm = fmaxf(rm, __shfl_xor(rm, 1));
        rm = fmaxf(rm, __shfl_xor(rm, 2));
        rm = fmaxf(rm, __shfl_xor(rm, 4));
        rm = fmaxf(rm, __shfl_xor(rm, 8));
        float mnew = fmaxf(m_r[reg], rm);
        float corr = __expf(m_r[reg] - mnew);
        m_r[reg] = mnew;
        float rs = 0.f;
        #pragma unroll
        for (int f = 0; f < 4; ++f){
          float p = __expf(s[f][reg] - mnew);
          s[f][reg] = p;
          rs += p;
        }
        rs += __shfl_xor(rs, 1);
        rs += __shfl_xor(rs, 2);
        rs += __shfl_xor(rs, 4);
        rs += __shfl_xor(rs, 8);
        l_r[reg] = l_r[reg]*corr + rs;
        #pragma unroll
        for (int df = 0; df < 4; ++df) o[df][reg] *= corr;
      }
      // P (C/D layout) -> LDS -> A-frag layout
      #pragma unroll
      for (int f = 0; f < 4; ++f)
        #pragma unroll
        for (int reg = 0; reg < 4; ++reg)
          P_lds[wv][lhi*4 + reg][f*16 + llo] = f2bs(s[f][reg]);
      bf16x8 pa0 = *reinterpret_cast<const bf16x8*>(&P_lds[wv][llo][lhi*8]);
      bf16x8 pa1 = *reinterpret_cast<const bf16x8*>(&P_lds[wv][llo][32 + lhi*8]);
      // PV: V^T rows give contiguous B-frags
      #pragma unroll
      for (int df = 0; df < 4; ++df){
        const short* vrow = &vT[((long)(b*H_SZ + df*16 + llo))*T_SZ + kv0 + lhi*8];
        bf16x8 vf0 = *reinterpret_cast<const bf16x8*>(vrow);
        bf16x8 vf1 = *reinterpret_cast<const bf16x8*>(vrow + 32);
        o[df] = __builtin_amdgcn_mfma_f32_16x16x32_bf16(pa0, vf0, o[df], 0, 0, 0);
        o[df] = __builtin_amdgcn_mfma_f32_16x16x32_bf16(pa1, vf1, o[df], 0, 0, 0);
      }
    }
    // normalize + store fp32
    #pragma unroll
    for (int df = 0; df < 4; ++df){
      #pragma unroll
      for (int reg = 0; reg < 4; ++reg){
        int q = q0 + lhi*4 + reg;
        out[((long)(b*T_SZ + q))*H_SZ + df*16 + llo] = o[df][reg] / l_r[reg];
      }
    }
  }
}

extern "C" void kernel_launch(void* const* d_in, const int* in_sizes, int n_in,
                              void* d_out, int out_size, void* d_ws, size_t ws_size,
                              hipStream_t stream){
  const float* x    = (const float*)d_in[0];
  const float* Wq   = (const float*)d_in[1];
  const float* Wk   = (const float*)d_in[2];
  const float* Wv   = (const float*)d_in[3];
  const float* bias = (const float*)d_in[4];
  float* out = (float*)d_out;

  const size_t NTOK = (size_t)B_SZ * T_SZ * H_SZ;   // 1,048,576
  short* qb = (short*)d_ws;
  short* kb = qb + NTOK;
  short* vT = kb + NTOK;
  short* Wt = vT + NTOK;                            // 192*768 shorts

  prep_wt<<<192, 256, 0, stream>>>(Wq, Wk, Wv, Wt);
  qkv_gemm<<<256, 512, 0, stream>>>(x, Wt, qb, kb, vT);
  attn_fwd<<<256, 128, 0, stream>>>(qb, kb, vT, bias, out);
}

// Round 2
// 92.913 us; speedup vs baseline: 1.7459x; 1.7459x over previous
//
#include <hip/hip_runtime.h>
#include <hip/hip_bf16.h>

typedef __attribute__((ext_vector_type(8))) short bf16x8;
typedef __attribute__((ext_vector_type(4))) short short4v;
typedef __attribute__((ext_vector_type(4))) float f32x4;

#define B_SZ 8
#define T_SZ 2048
#define C_SZ 768
#define H_SZ 64
#define WPB 8   // waves per attn block (KV-split width)

__device__ __forceinline__ short f2bs(float f){
  __hip_bfloat16 h = __float2bfloat16(f);
  short s; __builtin_memcpy(&s, &h, 2); return s;
}

// --- Kernel 0: W -> Wt[192][768] bf16 (transposed, q|k|v concatenated) ---
__global__ void prep_wt(const float* __restrict__ Wq, const float* __restrict__ Wk,
                        const float* __restrict__ Wv, short* __restrict__ Wt){
  int n = blockIdx.x;                       // 0..191 output column
  const float* W = (n < 64) ? Wq : (n < 128 ? Wk : Wv);
  int c = n & 63;
  for (int k = threadIdx.x; k < C_SZ; k += blockDim.x)
    Wt[n*C_SZ + k] = f2bs(W[k*H_SZ + c]);
}

// --- Kernel 1: QKV projection GEMM, BK=64 + register prefetch pipeline ---
__global__ __launch_bounds__(512) void qkv_gemm(const float* __restrict__ x, const short* __restrict__ Wt,
                         short* __restrict__ qb, short* __restrict__ kb, short* __restrict__ vT){
  __shared__ short As[64][72];              // +8 pad, 144B row stride (16B-aligned)
  int tid  = threadIdx.x;
  int wave = tid >> 6, lane = tid & 63;
  int lhi = lane >> 4, llo = lane & 15;
  int wm = wave >> 1, wn = wave & 1;        // 4 M-groups x 2 N-groups
  long m0 = (long)blockIdx.x * 64;

  f32x4 acc[6];
  #pragma unroll
  for (int j = 0; j < 6; ++j) acc[j] = (f32x4){0.f,0.f,0.f,0.f};

  int r = tid >> 3, koff = (tid & 7) * 8;   // staging: 8 floats/thread/iter
  const float* xrow = &x[(m0 + r)*C_SZ + koff];
  const short* aAddr = &As[wm*16 + llo][0];

  float4 n0 = *reinterpret_cast<const float4*>(xrow);
  float4 n1 = *reinterpret_cast<const float4*>(xrow + 4);

  for (int k0 = 0; k0 < C_SZ; k0 += 64){
    float4 c0 = n0, c1 = n1;
    if (k0 + 64 < C_SZ){                    // prefetch next tile; flies across MFMA phase
      n0 = *reinterpret_cast<const float4*>(xrow + k0 + 64);
      n1 = *reinterpret_cast<const float4*>(xrow + k0 + 68);
    }
    bf16x8 pk;
    pk[0]=f2bs(c0.x); pk[1]=f2bs(c0.y); pk[2]=f2bs(c0.z); pk[3]=f2bs(c0.w);
    pk[4]=f2bs(c1.x); pk[5]=f2bs(c1.y); pk[6]=f2bs(c1.z); pk[7]=f2bs(c1.w);
    *reinterpret_cast<bf16x8*>(&As[r][koff]) = pk;
    __syncthreads();
    #pragma unroll
    for (int ks = 0; ks < 2; ++ks){
      bf16x8 af = *reinterpret_cast<const bf16x8*>(aAddr + ks*32 + lhi*8);
      #pragma unroll
      for (int j = 0; j < 6; ++j){
        int n = wn*96 + j*16 + llo;
        bf16x8 bf = *reinterpret_cast<const bf16x8*>(&Wt[n*C_SZ + k0 + ks*32 + lhi*8]);
        acc[j] = __builtin_amdgcn_mfma_f32_16x16x32_bf16(af, bf, acc[j], 0, 0, 0);
      }
    }
    __syncthreads();
  }

  // epilogue: cols 0-63 -> q, 64-127 -> k, 128-191 -> v (transposed store)
  #pragma unroll
  for (int j = 0; j < 6; ++j){
    int n = wn*96 + j*16 + llo;
    int mat = n >> 6, c = n & 63;
    long mbase = m0 + wm*16 + lhi*4;
    if (mat == 2){
      long b = mbase >> 11, t = mbase & 2047;
      short4v p;
      #pragma unroll
      for (int reg = 0; reg < 4; ++reg) p[reg] = f2bs(acc[j][reg]);
      *reinterpret_cast<short4v*>(&vT[(b*H_SZ + c)*T_SZ + t]) = p;
    } else {
      short* dst = (mat == 0) ? qb : kb;
      #pragma unroll
      for (int reg = 0; reg < 4; ++reg)
        dst[(mbase + reg)*H_SZ + c] = f2bs(acc[j][reg]);
    }
  }
}

// --- Kernel 2: flash attention, 8-wave KV-split per q-tile, in-LDS merge ---
__global__ __launch_bounds__(512) void attn_fwd(const short* __restrict__ qb, const short* __restrict__ kb,
                        const short* __restrict__ vT, const float* __restrict__ bias_table,
                        float* __restrict__ out){
  __shared__ float bias_s[2048];            // 8 KB
  __shared__ float o_part[WPB][16][64];     // 32 KB
  __shared__ float m_part[WPB][16];
  __shared__ float l_part[WPB][16];
  __shared__ short P_lds[WPB][16][72];      // 18 KB, +8 pad

  int tid = threadIdx.x;
  for (int i = tid; i < 2048; i += 512) bias_s[i] = bias_table[i];

  int wv = tid >> 6, lane = tid & 63;
  int lhi = lane >> 4, llo = lane & 15;
  int wid = blockIdx.x;                     // 0..511
  int b = wid >> 6, jj = wid & 63;
  __syncthreads();

  for (int rep = 0; rep < 2; ++rep){
    int qt = (rep == 0) ? jj : (127 - jj);  // paired: per-block work ~constant
    int q0 = qt * 16;
    const short* qrow = &qb[((long)(b*T_SZ + q0 + llo))*H_SZ + lhi*8];
    bf16x8 qf0 = *reinterpret_cast<const bf16x8*>(qrow);
    bf16x8 qf1 = *reinterpret_cast<const bf16x8*>(qrow + 32);

    float m_r[4], l_r[4];
    f32x4 o[4];
    #pragma unroll
    for (int i2 = 0; i2 < 4; ++i2){ m_r[i2] = -1e30f; l_r[i2] = 0.f; o[i2] = (f32x4){0.f,0.f,0.f,0.f}; }

    int nkt = (qt >> 2) + 1;
    for (int kt = wv; kt < nkt; kt += WPB){ // KV-split across 8 waves
      int kv0 = kt * 64;
      f32x4 s[4];
      #pragma unroll
      for (int f = 0; f < 4; ++f){
        const short* krow = &kb[((long)(b*T_SZ + kv0 + f*16 + llo))*H_SZ + lhi*8];
        bf16x8 kf0 = *reinterpret_cast<const bf16x8*>(krow);
        bf16x8 kf1 = *reinterpret_cast<const bf16x8*>(krow + 32);
        f32x4 t = (f32x4){0.f,0.f,0.f,0.f};
        t = __builtin_amdgcn_mfma_f32_16x16x32_bf16(qf0, kf0, t, 0, 0, 0);
        t = __builtin_amdgcn_mfma_f32_16x16x32_bf16(qf1, kf1, t, 0, 0, 0);
        s[f] = t;
      }
      #pragma unroll
      for (int reg = 0; reg < 4; ++reg){
        int q = q0 + lhi*4 + reg;
        float rm = -1e30f;
        #pragma unroll
        for (int f = 0; f < 4; ++f){
          int kv = kv0 + f*16 + llo;
          int rel = q - kv;                 // causal => rel in [0,2047]
          float sv = (rel >= 0) ? (s[f][reg]*0.125f + bias_s[rel]) : -1e30f;
          s[f][reg] = sv;
          rm = fmaxf(rm, sv);
        }
        rm = fmaxf(rm, __shfl_xor(rm, 1));
        rm = fmaxf(rm, __shfl_xor(rm, 2));
        rm = fmaxf(rm, __shfl_xor(rm, 4));
        rm = fmaxf(rm, __shfl_xor(rm, 8));
        float mnew = fmaxf(m_r[reg], rm);
        float corr = __expf(m_r[reg] - mnew);
        m_r[reg] = mnew;
        float rs = 0.f;
        #pragma unroll
        for (int f = 0; f < 4; ++f){
          float p = __expf(s[f][reg] - mnew);
          s[f][reg] = p;
          rs += p;
        }
        rs += __shfl_xor(rs, 1);
        rs += __shfl_xor(rs, 2);
        rs += __shfl_xor(rs, 4);
        rs += __shfl_xor(rs, 8);
        l_r[reg] = l_r[reg]*corr + rs;
        #pragma unroll
        for (int df = 0; df < 4; ++df) o[df][reg] *= corr;
      }
      // P (C/D layout) -> LDS -> A-frag layout (wave-local)
      #pragma unroll
      for (int f = 0; f < 4; ++f)
        #pragma unroll
        for (int reg = 0; reg < 4; ++reg)
          P_lds[wv][lhi*4 + reg][f*16 + llo] = f2bs(s[f][reg]);
      bf16x8 pa0 = *reinterpret_cast<const bf16x8*>(&P_lds[wv][llo][lhi*8]);
      bf16x8 pa1 = *reinterpret_cast<const bf16x8*>(&P_lds[wv][llo][32 + lhi*8]);
      #pragma unroll
      for (int df = 0; df < 4; ++df){
        const short* vrow = &vT[((long)(b*H_SZ + df*16 + llo))*T_SZ + kv0 + lhi*8];
        bf16x8 vf0 = *reinterpret_cast<const bf16x8*>(vrow);
        bf16x8 vf1 = *reinterpret_cast<const bf16x8*>(vrow + 32);
        o[df] = __builtin_amdgcn_mfma_f32_16x16x32_bf16(pa0, vf0, o[df], 0, 0, 0);
        o[df] = __builtin_amdgcn_mfma_f32_16x16x32_bf16(pa1, vf1, o[df], 0, 0, 0);
      }
    }

    // write flash partials to LDS
    #pragma unroll
    for (int df = 0; df < 4; ++df)
      #pragma unroll
      for (int reg = 0; reg < 4; ++reg)
        o_part[wv][lhi*4 + reg][df*16 + llo] = o[df][reg];
    if (llo == 0){
      #pragma unroll
      for (int reg = 0; reg < 4; ++reg){
        m_part[wv][lhi*4 + reg] = m_r[reg];
        l_part[wv][lhi*4 + reg] = l_r[reg];
      }
    }
    __syncthreads();

    // merge 8 partials: 512 threads x 2 outputs each
    #pragma unroll
    for (int i = 0; i < 2; ++i){
      int p = tid + i*512;
      int row = p >> 6, col = p & 63;
      float mstar = -1e30f;
      #pragma unroll
      for (int w = 0; w < WPB; ++w) mstar = fmaxf(mstar, m_part[w][row]);
      float osum = 0.f, lsum = 0.f;
      #pragma unroll
      for (int w = 0; w < WPB; ++w){
        float sc = __expf(m_part[w][row] - mstar);
        lsum += l_part[w][row] * sc;
        osum += o_part[w][row][col] * sc;
      }
      out[((long)(b*T_SZ + q0 + row))*H_SZ + col] = osum / lsum;
    }
    __syncthreads();                        // LDS reused next rep
  }
}

extern "C" void kernel_launch(void* const* d_in, const int* in_sizes, int n_in,
                              void* d_out, int out_size, void* d_ws, size_t ws_size,
                              hipStream_t stream){
  const float* x    = (const float*)d_in[0];
  const float* Wq   = (const float*)d_in[1];
  const float* Wk   = (const float*)d_in[2];
  const float* Wv   = (const float*)d_in[3];
  const float* bias = (const float*)d_in[4];
  float* out = (float*)d_out;

  const size_t NTOK = (size_t)B_SZ * T_SZ * H_SZ;   // 1,048,576
  short* qb = (short*)d_ws;
  short* kb = qb + NTOK;
  short* vT = kb + NTOK;
  short* Wt = vT + NTOK;                            // 192*768 shorts

  prep_wt<<<192, 256, 0, stream>>>(Wq, Wk, Wv, Wt);
  qkv_gemm<<<256, 512, 0, stream>>>(x, Wt, qb, kb, vT);
  attn_fwd<<<512, 512, 0, stream>>>(qb, kb, vT, bias, out);
}